// Round 10
// baseline (2542.136 us; speedup 1.0000x reference)
//
#include <hip/hip_runtime.h>

// SparseGCNConv: out = segment_sum(norm * f[src], dst, N) @ W^T + bias
// R14 (resubmit; prior bench aborted on container-acquire infra failure,
// same as R1's precedent): DELETE the per-node sort. pull becomes pullb:
// one block per 64-node bucket, 32KB LDS f32 accumulators, ds_add_f32
// atomics; consumes bin's bucket-grouped bufA directly. bufB + row_ptr +
// sort are gone (-51MB traffic, -1 dispatch). Buckets back to 64 nodes
// (dlocal 6b @ bit 17). bin keeps proven 1024-thr shape; gemm rides in
// bin's launch at 16 waves/block (R12's regression was bin@256thr).
//  D1 = hist ∥ cvtw, D2 = scan(1563), D3 = bin ∥ gemm, D4 = pullb.

#define NN    100000
#define NE    3200000
#define D     128
#define NBKT  1563   // ceil(NN/64); bucket b = dst >> 6
#define NI4   800000 // NE/4 int4 elements
#define NTILE 6250   // NN/16 node tiles (exact)
#define HB    782    // hist blocks (782*1024 int4 >= 800000)
#define BINB  196    // bin blocks  (196*4096 int4 >= 800000)
#define GB3   391    // gemm blocks (391*16 waves >= 6250 tiles)

typedef __attribute__((ext_vector_type(8))) short bf16x8;
typedef __attribute__((ext_vector_type(4))) float f32x4;

static __device__ __forceinline__ unsigned short f2bf(float x) {
  unsigned u = __float_as_uint(x);
  u += 0x7FFFu + ((u >> 16) & 1u);  // RTNE
  return (unsigned short)(u >> 16);
}

// r[j] = f16(q)[j] * nr  (fma_mix with 0 addend; no unpack instructions)
static __device__ __forceinline__ void mixmul8(float* r, uint4 q, float nr) {
  float zz = 0.f;
  asm("v_fma_mix_f32 %0, %1, %2, %3 op_sel:[0,0,0] op_sel_hi:[1,0,0]"
      : "=v"(r[0]) : "v"(q.x), "v"(nr), "v"(zz));
  asm("v_fma_mix_f32 %0, %1, %2, %3 op_sel:[1,0,0] op_sel_hi:[1,0,0]"
      : "=v"(r[1]) : "v"(q.x), "v"(nr), "v"(zz));
  asm("v_fma_mix_f32 %0, %1, %2, %3 op_sel:[0,0,0] op_sel_hi:[1,0,0]"
      : "=v"(r[2]) : "v"(q.y), "v"(nr), "v"(zz));
  asm("v_fma_mix_f32 %0, %1, %2, %3 op_sel:[1,0,0] op_sel_hi:[1,0,0]"
      : "=v"(r[3]) : "v"(q.y), "v"(nr), "v"(zz));
  asm("v_fma_mix_f32 %0, %1, %2, %3 op_sel:[0,0,0] op_sel_hi:[1,0,0]"
      : "=v"(r[4]) : "v"(q.z), "v"(nr), "v"(zz));
  asm("v_fma_mix_f32 %0, %1, %2, %3 op_sel:[1,0,0] op_sel_hi:[1,0,0]"
      : "=v"(r[5]) : "v"(q.z), "v"(nr), "v"(zz));
  asm("v_fma_mix_f32 %0, %1, %2, %3 op_sel:[0,0,0] op_sel_hi:[1,0,0]"
      : "=v"(r[6]) : "v"(q.w), "v"(nr), "v"(zz));
  asm("v_fma_mix_f32 %0, %1, %2, %3 op_sel:[1,0,0] op_sel_hi:[1,0,0]"
      : "=v"(r[7]) : "v"(q.w), "v"(nr), "v"(zz));
}

// ---------------------------------------------------------------------------
// D1: blocks [0,HB) = 64-node bucket histogram; blocks [HB,HB+64) = W
// fp32->bf16 fragment conversion (independent inputs).
__global__ __launch_bounds__(256) void histcvt_kernel(
    const int* __restrict__ dst, int* __restrict__ gcnt,
    const float* __restrict__ w, unsigned short* __restrict__ wfrag) {
  __shared__ int h[4][NBKT];
  const int t = threadIdx.x;
  if (blockIdx.x >= HB) {
    const int i = (blockIdx.x - HB) * 256 + t;  // 16384 elems, 64 blocks
    const int c = i >> 7, k = i & 127;
    const int pos = ((((c >> 4) << 2) + (k >> 5)) * 64 +
                     (((k >> 3) & 3) << 4) + (c & 15)) * 8 + (k & 7);
    wfrag[pos] = f2bf(w[i]);
    return;
  }
  for (int i = t; i < 4 * NBKT; i += 256) ((int*)h)[i] = 0;
  __syncthreads();
  const int i4base = blockIdx.x * 1024;
  const int rep = t & 3;
#pragma unroll
  for (int i = 0; i < 4; ++i) {
    const int idx = i4base + i * 256 + t;
    if (idx < NI4) {
      const int4 d = ((const int4*)dst)[idx];
      atomicAdd(&h[rep][d.x >> 6], 1);
      atomicAdd(&h[rep][d.y >> 6], 1);
      atomicAdd(&h[rep][d.z >> 6], 1);
      atomicAdd(&h[rep][d.w >> 6], 1);
    }
  }
  __syncthreads();
  for (int b = t; b < NBKT; b += 256) {
    const int v = h[0][b] + h[1][b] + h[2][b] + h[3][b];
    if (v) atomicAdd(&gcnt[b], v);
  }
}

// ---------------------------------------------------------------------------
// D2: exclusive scan of 1563 bucket counts -> bstart + cur_b. (R5-proven)
__global__ __launch_bounds__(1024) void scan_kernel(const int* __restrict__ gcnt,
                                                    int* __restrict__ bstart,
                                                    int* __restrict__ cur_b) {
  __shared__ int s[2048];
  const int t = threadIdx.x;
  s[t] = (t < NBKT) ? gcnt[t] : 0;
  s[t + 1024] = (t + 1024 < NBKT) ? gcnt[t + 1024] : 0;
  __syncthreads();
  if (t < 64) {
    int part = 0;
#pragma unroll
    for (int i = 0; i < 32; ++i) part += s[(t << 5) + i];
    int inc = part;
#pragma unroll
    for (int off = 1; off < 64; off <<= 1) {
      int x = __shfl_up(inc, off, 64);
      if (t >= off) inc += x;
    }
    int run = inc - part;
#pragma unroll
    for (int i = 0; i < 32; ++i) {
      int idx = (t << 5) + i;
      int v = s[idx];
      s[idx] = run;
      run += v;
    }
  }
  __syncthreads();
  if (t < NBKT) { bstart[t] = s[t]; cur_b[t] = s[t]; }
  if (t + 1024 < NBKT) { bstart[t + 1024] = s[t + 1024]; cur_b[t + 1024] = s[t + 1024]; }
  if (t == 0) bstart[NBKT] = NE;
}

// ---------------------------------------------------------------------------
// D3: blocks [0,BINB) = bin into 64-node buckets (1024 thr, proven shape;
// all per-bucket ops strided: 1024 < 1563). blocks [BINB,BINB+GB3) = MFMA
// gemm at 16 waves/block. bin first so it starts at t=0.
// Pack: m.x = src | ((dst & 63) << 17)  (src < 2^17).
__global__ __launch_bounds__(1024) void bingemm_kernel(
    const int* __restrict__ src, const int* __restrict__ dst,
    const float* __restrict__ norm, int* __restrict__ cur_b,
    int2* __restrict__ bufA, const float* __restrict__ f,
    const unsigned short* __restrict__ wfrag, unsigned short* __restrict__ gh) {
  __shared__ int bcnt[4][NBKT];
  __shared__ int bbase[NBKT];
  __shared__ int brank[NBKT];
  const int t = threadIdx.x;
  if (blockIdx.x < BINB) {
    for (int i = t; i < 4 * NBKT; i += 1024) ((int*)bcnt)[i] = 0;
    for (int b = t; b < NBKT; b += 1024) brank[b] = 0;  // strided: 1024<1563
    __syncthreads();
    const int i4base = blockIdx.x * 4096;
    const int rep = t & 3;
#pragma unroll
    for (int i = 0; i < 4; ++i) {
      const int idx = i4base + i * 1024 + t;
      if (idx < NI4) {
        const int4 d = ((const int4*)dst)[idx];
        atomicAdd(&bcnt[rep][d.x >> 6], 1);
        atomicAdd(&bcnt[rep][d.y >> 6], 1);
        atomicAdd(&bcnt[rep][d.z >> 6], 1);
        atomicAdd(&bcnt[rep][d.w >> 6], 1);
      }
    }
    __syncthreads();
    for (int b = t; b < NBKT; b += 1024) {  // strided: 1024 < 1563
      const int c = bcnt[0][b] + bcnt[1][b] + bcnt[2][b] + bcnt[3][b];
      if (c) bbase[b] = atomicAdd(&cur_b[b], c);
    }
    __syncthreads();
#pragma unroll
    for (int i = 0; i < 4; ++i) {
      const int idx = i4base + i * 1024 + t;
      if (idx < NI4) {
        const int4 s = ((const int4*)src)[idx];
        const int4 d = ((const int4*)dst)[idx];
        const float4 nr = ((const float4*)norm)[idx];
        int bb, r; int2 m;
        bb = d.x >> 6; r = atomicAdd(&brank[bb], 1);
        m.x = s.x | ((d.x & 63) << 17); m.y = __float_as_int(nr.x);
        bufA[bbase[bb] + r] = m;
        bb = d.y >> 6; r = atomicAdd(&brank[bb], 1);
        m.x = s.y | ((d.y & 63) << 17); m.y = __float_as_int(nr.y);
        bufA[bbase[bb] + r] = m;
        bb = d.z >> 6; r = atomicAdd(&brank[bb], 1);
        m.x = s.z | ((d.z & 63) << 17); m.y = __float_as_int(nr.z);
        bufA[bbase[bb] + r] = m;
        bb = d.w >> 6; r = atomicAdd(&brank[bb], 1);
        m.x = s.w | ((d.w & 63) << 17); m.y = __float_as_int(nr.w);
        bufA[bbase[bb] + r] = m;
      }
    }
    return;
  }

  const int wv = (blockIdx.x - BINB) * 16 + (t >> 6);
  if (wv >= NTILE) return;
  const int lane = t & 63;
  const int mrow = lane & 15;
  const int q = lane >> 4;
  const long node = (long)wv * 16 + mrow;
  const float* fr = f + node * D + q * 8;

  bf16x8 a[4];
#pragma unroll
  for (int ks = 0; ks < 4; ++ks) {
    const float4 lo = *(const float4*)(fr + ks * 32);
    const float4 hi = *(const float4*)(fr + ks * 32 + 4);
    union { bf16x8 v; unsigned short u[8]; } pa;
    pa.u[0] = f2bf(lo.x); pa.u[1] = f2bf(lo.y);
    pa.u[2] = f2bf(lo.z); pa.u[3] = f2bf(lo.w);
    pa.u[4] = f2bf(hi.x); pa.u[5] = f2bf(hi.y);
    pa.u[6] = f2bf(hi.z); pa.u[7] = f2bf(hi.w);
    a[ks] = pa.v;
  }

  const long nbase = (long)wv * 16 + (q << 2);
#pragma unroll
  for (int tc = 0; tc < 8; ++tc) {
    f32x4 acc = {0.f, 0.f, 0.f, 0.f};
#pragma unroll
    for (int ks = 0; ks < 4; ++ks) {
      const bf16x8 b =
          *(const bf16x8*)(wfrag + (((tc << 2) + ks) * 64 + lane) * 8);
      acc = __builtin_amdgcn_mfma_f32_16x16x32_bf16(a[ks], b, acc, 0, 0, 0);
    }
    const int c = (tc << 4) + mrow;
#pragma unroll
    for (int r = 0; r < 4; ++r) {
      union { _Float16 hh; unsigned short u; } cv;
      cv.hh = (_Float16)acc[r];  // v_cvt_f16_f32, RTNE
      gh[(nbase + r) * D + c] = cv.u;
    }
  }
}

// ---------------------------------------------------------------------------
// D4: pullb -- one block per 64-node bucket. 32KB LDS f32 accumulators;
// 16 lanes/edge dwordx4 f16 gathers (proven); fma_mix multiply; ds_add_f32
// into accs[dlocal][ch]. Clamped lanes add 0 (valid address, nr=0).
// Writeout: accs + bias -> out, coalesced float4, n<NN guard.
__global__ __launch_bounds__(256) void pullb_kernel(
    const unsigned short* __restrict__ gh, const int* __restrict__ bstart,
    const int2* __restrict__ bufA, const float* __restrict__ bias,
    float* __restrict__ out) {
  __shared__ float accs[64 * 128];  // 32 KB
  const int t = threadIdx.x;
  float4* a4 = (float4*)accs;
#pragma unroll
  for (int i = 0; i < 8; ++i) a4[i * 256 + t] = make_float4(0.f, 0.f, 0.f, 0.f);
  __syncthreads();
  const int b = blockIdx.x;
  const int beg = bstart[b];
  const int end = bstart[b + 1];
  const int lane = t & 63;
  const int s = lane & 15;   // sublane: channels s*8 .. s*8+7
  const int g = lane >> 4;   // edge group
  const int w = t >> 6;      // wave id 0..3
  const char* gbase = (const char*)gh;
  const unsigned soff = (unsigned)(s << 4);  // byte offset within 256B row

  for (int e0 = beg + w * 8; e0 < end; e0 += 32) {
    const int last = end - 1;
    const int eA = e0 + g;
    const int eB = e0 + 4 + g;
    const int2 mA = bufA[min(eA, last)];
    const int2 mB = bufA[min(eB, last)];
    const uint4 qA =
        *(const uint4*)(gbase + (((unsigned)(mA.x & 0x1FFFF)) << 8) + soff);
    const uint4 qB =
        *(const uint4*)(gbase + (((unsigned)(mB.x & 0x1FFFF)) << 8) + soff);
    const float nrA = (eA < end) ? __int_as_float(mA.y) : 0.f;
    const float nrB = (eB < end) ? __int_as_float(mB.y) : 0.f;
    float rA[8], rB[8];
    mixmul8(rA, qA, nrA);
    mixmul8(rB, qB, nrB);
    float* pA = accs + (((mA.x >> 17) & 63) << 7) + (s << 3);
    float* pB = accs + (((mB.x >> 17) & 63) << 7) + (s << 3);
#pragma unroll
    for (int j = 0; j < 8; ++j) atomicAdd(pA + j, rA[j]);
#pragma unroll
    for (int j = 0; j < 8; ++j) atomicAdd(pB + j, rB[j]);
  }
  __syncthreads();

  const int nbase = b << 6;
  const float4* b4 = (const float4*)bias;
  float4* o4 = (float4*)out;
#pragma unroll
  for (int i = 0; i < 8; ++i) {
    const int idx = i * 256 + t;        // float4 index in LDS (2048 total)
    const int n = nbase + (idx >> 5);   // 32 float4 per node row
    if (n < NN) {
      const int c4 = idx & 31;
      float4 v = a4[idx];
      const float4 bb = b4[c4];
      v.x += bb.x; v.y += bb.y; v.z += bb.z; v.w += bb.w;
      o4[((long)n << 5) + c4] = v;
    }
  }
}

// ---------------------------------------------------------------------------
// Fallback (ws too small): R1 path.
__global__ __launch_bounds__(256) void gemm_f32_kernel(
    const float* __restrict__ f, const float* __restrict__ w,
    float* __restrict__ g) {
  __shared__ float wlds[D * D];
  const int t = threadIdx.x;
  for (int i = t; i < D * D; i += 256) {
    int c = i >> 7, k = i & 127;
    wlds[(c << 7) + (k ^ (c & 31))] = w[i];
  }
  __syncthreads();
  const int c = t & 127;
  const int cx = c & 31;
  const int cbase = c << 7;
  const int jbase = __builtin_amdgcn_readfirstlane((t >> 7) << 3);
  const long nb = (long)blockIdx.x * 16 + jbase;
  const float* __restrict__ frow = f + nb * D;
  float acc[8] = {0.f, 0.f, 0.f, 0.f, 0.f, 0.f, 0.f, 0.f};
#pragma unroll 4
  for (int k = 0; k < D; ++k) {
    float wv = wlds[cbase + (k ^ cx)];
#pragma unroll
    for (int j = 0; j < 8; ++j) acc[j] += frow[j * D + k] * wv;
  }
#pragma unroll
  for (int j = 0; j < 8; ++j) g[(nb + j) * D + c] = acc[j];
}

__global__ __launch_bounds__(256) void init_kernel(
    const float* __restrict__ bias, float4* __restrict__ out) {
  const int i = blockIdx.x * 256 + threadIdx.x;
  const float4* b4 = (const float4*)bias;
  out[i] = b4[i & 31];
}

__global__ __launch_bounds__(256) void scatter_kernel(
    const float* __restrict__ g, const float* __restrict__ norm,
    const int* __restrict__ src, const int* __restrict__ dst,
    float* __restrict__ out) {
  const long tid = (long)blockIdx.x * 256 + threadIdx.x;
  const int e = (int)(tid >> 5);
  if (e >= NE) return;
  const int ch = (int)(tid & 31) << 2;
  const int s = src[e];
  const int d = dst[e];
  const float nr = norm[e];
  const float4 gv = *(const float4*)(g + (long)s * D + ch);
  float* op = out + (long)d * D + ch;
  unsafeAtomicAdd(op + 0, nr * gv.x);
  unsafeAtomicAdd(op + 1, nr * gv.y);
  unsafeAtomicAdd(op + 2, nr * gv.z);
  unsafeAtomicAdd(op + 3, nr * gv.w);
}

// ---------------------------------------------------------------------------
extern "C" void kernel_launch(void* const* d_in, const int* in_sizes, int n_in,
                              void* d_out, int out_size, void* d_ws,
                              size_t ws_size, hipStream_t stream) {
  const float* features = (const float*)d_in[0];
  const float* norm     = (const float*)d_in[1];
  const int*   src      = (const int*)d_in[2];
  const int*   dst      = (const int*)d_in[3];
  const float* weight   = (const float*)d_in[4];
  const float* bias     = (const float*)d_in[5];
  float* out = (float*)d_out;

  char* ws = (char*)d_ws;
  unsigned short* gh    = (unsigned short*)ws;   // [0, 25.6M)  f16 g-matrix
  int2* bufA    = (int2*)(ws + 25600000);        // [25.6M, 51.2M)
  int*  gcnt    = (int*)(ws + 51200000);         // 6,252 B
  int*  bstart  = (int*)(ws + 51206256);         // 6,256 B
  int*  cur_b   = (int*)(ws + 51212512);         // 6,252 B
  unsigned short* wfrag = (unsigned short*)(ws + 51218768);  // 32,768 B
  const size_t need = 51251536;                  // ws >= 77,602,176 proven (R2)

  if (ws_size >= need) {
    hipMemsetAsync(gcnt, 0, NBKT * sizeof(int), stream);
    hipLaunchKernelGGL(histcvt_kernel, dim3(HB + 64), dim3(256), 0, stream,
                       dst, gcnt, weight, wfrag);
    hipLaunchKernelGGL(scan_kernel, dim3(1), dim3(1024), 0, stream,
                       gcnt, bstart, cur_b);
    hipLaunchKernelGGL(bingemm_kernel, dim3(BINB + GB3), dim3(1024), 0, stream,
                       src, dst, norm, cur_b, bufA, features, wfrag, gh);
    hipLaunchKernelGGL(pullb_kernel, dim3(NBKT), dim3(256), 0, stream,
                       gh, bstart, bufA, bias, out);
  } else {
    float* g = (float*)ws;
    hipLaunchKernelGGL(gemm_f32_kernel, dim3(NN / 16), dim3(256), 0, stream,
                       features, weight, g);
    hipLaunchKernelGGL(init_kernel, dim3((NN * D / 4) / 256), dim3(256), 0,
                       stream, bias, (float4*)out);
    hipLaunchKernelGGL(scatter_kernel, dim3((long)NE * 32 / 256), dim3(256), 0,
                       stream, g, norm, src, dst, out);
  }
}